// Round 2
// baseline (100.555 us; speedup 1.0000x reference)
//
#include <hip/hip_runtime.h>

// ChamferLoss: x,y (16,4096,3) f32 -> scalar.
// R10: LDS-pipe + VALU-width fix. R9 showed doubling occupancy (17->30%)
// changed nothing -> pipe-bound, not latency-bound. ds_read_b128 spacing
// measured 13.9 cyc ~ the 12 cyc b128 throughput => LDS-instr bound.
// Changes:
//  1) RQ 4->8 with DB split across wave pairs (waves 2k/2k+1 share 64
//     queries, each scans half the DB; mins combined via 1KB LDS).
//     Halves LDS reads per pair-eval while keeping 4096 waves = 4/SIMD.
//  2) v_pk_fma_f32: LDS tile stored as point-pairs (x0,x1,y0,y1) +
//     (z0,z1,d2_0,d2_1); 2 db points per packed FMA chain. VALU ops per
//     pair-eval 3.5 -> 2 (3 pk_fma + 1 min3 per 2 points).
// Floors: VALU 13.7us, LDS 7-20us. Target 26-32us.

#define NP 4096
#define NB 16
#define BLK 512
#define RQ 8                    // queries per lane
#define QPB 256                 // queries per block (4 wave-pairs * 8 tq * RQ)
#define BPZ (NP / QPB)          // 16 blocks per zz
#define NZZ (2 * NB)            // 32 (dir,b)
#define NBLOCKS (NZZ * BPZ)     // 512 = 2 blocks/CU

typedef float v2f __attribute__((ext_vector_type(2)));

__global__ void chamfer_init(float* __restrict__ out) { out[0] = 0.0f; }

__device__ __forceinline__ float fmin3(float a, float b, float c) {
  float d;
  asm("v_min3_f32 %0, %1, %2, %3" : "=v"(d) : "v"(a), "v"(b), "v"(c));
  return d;
}

__device__ __forceinline__ v2f pk_fma(v2f a, v2f b, v2f c) {
  v2f d;
  asm("v_pk_fma_f32 %0, %1, %2, %3" : "=v"(d) : "v"(a), "v"(b), "v"(c));
  return d;
}

__global__ __launch_bounds__(BLK, 4) void chamfer_main(
    const float* __restrict__ x, const float* __restrict__ y,
    float* __restrict__ out) {
  const int bid  = blockIdx.x;
  const int zz   = bid >> 4;          // /BPZ
  const int qblk = bid & (BPZ - 1);
  const int dir  = zz >> 4;
  const int b    = zz & 15;

  const float* q_base = (dir == 0 ? x : y) + (size_t)b * NP * 3;
  const float* d_base = (dir == 0 ? y : x) + (size_t)b * NP * 3;

  const int wid  = threadIdx.x >> 6;  // wave 0..7
  const int lane = threadIdx.x & 63;
  const int wp   = wid >> 1;          // wave pair 0..3 (shares queries)
  const int h    = wid & 1;           // db half 0/1
  const int td   = lane & 7;          // db slice within half
  const int tq   = lane >> 3;         // query group 0..7

  // ---- this lane's RQ queries (issue global loads early) ----
  v2f qx2[RQ], qy2[RQ], qz2[RQ];
  float q2[RQ], m[RQ];
#pragma unroll
  for (int r = 0; r < RQ; ++r) {
    const int qi = qblk * QPB + wp * 64 + tq * RQ + r;
    const float qx = q_base[qi * 3 + 0];
    const float qy = q_base[qi * 3 + 1];
    const float qz = q_base[qi * 3 + 2];
    q2[r]  = qx * qx + qy * qy + qz * qz;
    const float cx = -2.0f * qx, cy = -2.0f * qy, cz = -2.0f * qz;
    qx2[r] = (v2f){cx, cx};
    qy2[r] = (v2f){cy, cy};
    qz2[r] = (v2f){cz, cz};
    m[r]   = 3.4e38f;
  }

  // ---- stage full db into LDS as point-pairs:
  //      dptp[2u]   = (x0, x1, y0, y1)
  //      dptp[2u+1] = (z0, z1, d2_0, d2_1)   for points 2u, 2u+1 ----
  __shared__ float4 dptp[NP];         // 64 KB
  for (int u = threadIdx.x; u < NP / 2; u += BLK) {
    const float2 f0 = *(const float2*)(d_base + u * 6 + 0);  // ax, ay
    const float2 f1 = *(const float2*)(d_base + u * 6 + 2);  // az, bx
    const float2 f2 = *(const float2*)(d_base + u * 6 + 4);  // by, bz
    const float ax = f0.x, ay = f0.y, az = f1.x;
    const float bx = f1.y, by = f2.x, bz = f2.y;
    dptp[2 * u + 0] = make_float4(ax, bx, ay, by);
    dptp[2 * u + 1] = make_float4(az, bz,
                                  ax * ax + ay * ay + az * az,
                                  bx * bx + by * by + bz * bz);
  }
  __syncthreads();

  // ---- min over this lane's db slice: pairs u = i*16 + (h*8+td) ----
  const int sl = h * 8 + td;          // 0..15
#pragma unroll 2
  for (int i = 0; i < NP / 32; ++i) { // 128 iterations, 2 points each
    const float4 A = dptp[(i * 16 + sl) * 2 + 0];
    const float4 B = dptp[(i * 16 + sl) * 2 + 1];
    const v2f xs = {A.x, A.y};
    const v2f ys = {A.z, A.w};
    const v2f zs = {B.x, B.y};
    const v2f w2 = {B.z, B.w};
#pragma unroll
    for (int r = 0; r < RQ; ++r) {
      const v2f dv = pk_fma(xs, qx2[r], pk_fma(ys, qy2[r], pk_fma(zs, qz2[r], w2)));
      m[r] = fmin3(dv.x, dv.y, m[r]);
    }
  }

  // ---- reduce mins across the 8 td lanes of each octet ----
#pragma unroll
  for (int r = 0; r < RQ; ++r) {
    m[r] = fminf(m[r], __shfl_xor(m[r], 1));
    m[r] = fminf(m[r], __shfl_xor(m[r], 2));
    m[r] = fminf(m[r], __shfl_xor(m[r], 4));
  }

  // ---- combine the two db-halves of each wave pair via LDS ----
  __shared__ float pm[4][64];         // [wp][tq*RQ + r], 1 KB
  if (h == 1 && td == 0) {
#pragma unroll
    for (int r = 0; r < RQ; ++r) pm[wp][tq * RQ + r] = m[r];
  }
  __syncthreads();

  // ---- epilogue: sqrt + partial mean (h==0, td==0 lanes only) ----
  float local = 0.0f;
  if (h == 0 && td == 0) {
#pragma unroll
    for (int r = 0; r < RQ; ++r) {
      const float mr = fminf(m[r], pm[wp][tq * RQ + r]);
      local += sqrtf(fmaxf(q2[r] + mr, 0.0f) + 1e-6f);
    }
    local *= (1.0f / (float)(NB * NP));
  }

  // wave reduce, then block reduce, one atomic per block
#pragma unroll
  for (int off = 32; off > 0; off >>= 1)
    local += __shfl_down(local, off);

  __shared__ float wsum[BLK / 64];
  if (lane == 0) wsum[wid] = local;
  __syncthreads();
  if (threadIdx.x == 0) {
    float s = 0.0f;
#pragma unroll
    for (int w = 0; w < BLK / 64; ++w) s += wsum[w];
    atomicAdd(out, s);
  }
}

extern "C" void kernel_launch(void* const* d_in, const int* in_sizes, int n_in,
                              void* d_out, int out_size, void* d_ws, size_t ws_size,
                              hipStream_t stream) {
  const float* x = (const float*)d_in[0];
  const float* y = (const float*)d_in[1];
  float* out = (float*)d_out;

  chamfer_init<<<1, 64, 0, stream>>>(out);
  chamfer_main<<<NBLOCKS, BLK, 0, stream>>>(x, y, out);
}

// Round 3
// 99.174 us; speedup vs baseline: 1.0139x; 1.0139x over previous
//
#include <hip/hip_runtime.h>

// ChamferLoss: x,y (16,4096,3) f32 -> scalar.
// R11: R10 post-mortem: pk_fma asm + 32B-stride pair layout went
// stall-bound (VALUBusy 106->58 but dur 47->54, 262K bank conflicts).
// Revert to scalar fmaf + conflict-free 16B-stride float4 layout (R8/R9
// form, proven ~48us) and fix the R9 bottleneck (LDS pipe: 8192 reads/CU
// x 12cyc = 41us) by raising intensity per read:
//   RQ 4->16, DB split 4 ways across each wave quad (waves 4k..4k+3 share
//   128 queries, each scans 1024 db pts; mins combined via 3KB LDS).
// Per-CU floors: LDS 2048 reads x 12cyc = 10.2us; VALU 7168 instr/wave
// x 16 waves / 4 SIMD x 2cyc = 23.9us. 4 waves/SIMD hides latency.
// Target 27-32us.

#define NP 4096
#define NB 16
#define BLK 512
#define RQ 16                   // queries per lane
#define QPB 256                 // 2 quads * 8 tq * RQ
#define BPZ (NP / QPB)          // 16 blocks per zz
#define NZZ (2 * NB)            // 32 (dir,b)
#define NBLOCKS (NZZ * BPZ)     // 512 = 2 blocks/CU

__global__ void chamfer_init(float* __restrict__ out) { out[0] = 0.0f; }

__device__ __forceinline__ float fmin3(float a, float b, float c) {
  float d;
  asm("v_min3_f32 %0, %1, %2, %3" : "=v"(d) : "v"(a), "v"(b), "v"(c));
  return d;
}

__global__ __launch_bounds__(BLK, 4) void chamfer_main(
    const float* __restrict__ x, const float* __restrict__ y,
    float* __restrict__ out) {
  const int bid  = blockIdx.x;
  const int zz   = bid >> 4;          // /BPZ
  const int qblk = bid & (BPZ - 1);
  const int dir  = zz >> 4;
  const int b    = zz & 15;

  const float* q_base = (dir == 0 ? x : y) + (size_t)b * NP * 3;
  const float* d_base = (dir == 0 ? y : x) + (size_t)b * NP * 3;

  const int wid  = threadIdx.x >> 6;  // wave 0..7
  const int lane = threadIdx.x & 63;
  const int wq   = wid >> 2;          // wave quad 0..1 (shares 128 queries)
  const int h    = wid & 3;           // db quarter 0..3
  const int td   = lane & 7;          // db slice 0..7
  const int tq   = lane >> 3;         // query group 0..7

  // ---- this lane's RQ queries ----
  float qpx[RQ], qpy[RQ], qpz[RQ], q2[RQ], m[RQ];
#pragma unroll
  for (int r = 0; r < RQ; ++r) {
    const int qi = qblk * QPB + wq * 128 + tq * RQ + r;
    const float qx = q_base[qi * 3 + 0];
    const float qy = q_base[qi * 3 + 1];
    const float qz = q_base[qi * 3 + 2];
    q2[r]  = qx * qx + qy * qy + qz * qz;
    qpx[r] = -2.0f * qx;
    qpy[r] = -2.0f * qy;
    qpz[r] = -2.0f * qz;
    m[r]   = 3.4e38f;
  }

  // ---- stage full db (4096 pts) into LDS as (x,y,z,d2), 16B stride ----
  __shared__ float4 dpt[NP];          // 64 KB
  for (int p = threadIdx.x; p < NP; p += BLK) {
    const float dx = d_base[p * 3 + 0];
    const float dy = d_base[p * 3 + 1];
    const float dz = d_base[p * 3 + 2];
    dpt[p] = make_float4(dx, dy, dz, dx * dx + dy * dy + dz * dz);
  }
  __syncthreads();

  // ---- min over this lane's db slice: p = t*32 + h*8 + td, t in [0,128) ----
  const int off = h * 8 + td;
#pragma unroll 2
  for (int t = 0; t < NP / 32; t += 2) {
    const float4 d0 = dpt[t * 32 + off];
    const float4 d1 = dpt[(t + 1) * 32 + off];
#pragma unroll
    for (int r = 0; r < RQ; ++r) {
      const float v0 = fmaf(d0.x, qpx[r], fmaf(d0.y, qpy[r], fmaf(d0.z, qpz[r], d0.w)));
      const float v1 = fmaf(d1.x, qpx[r], fmaf(d1.y, qpy[r], fmaf(d1.z, qpz[r], d1.w)));
      m[r] = fmin3(v0, v1, m[r]);
    }
  }

  // ---- reduce mins across the 8 td lanes of each octet ----
#pragma unroll
  for (int r = 0; r < RQ; ++r) {
    m[r] = fminf(m[r], __shfl_xor(m[r], 1));
    m[r] = fminf(m[r], __shfl_xor(m[r], 2));
    m[r] = fminf(m[r], __shfl_xor(m[r], 4));
  }

  // ---- combine the four db-quarters of each wave quad via LDS ----
  __shared__ float pm[3][2][128];     // [h-1][wq][tq*RQ+r], 3 KB
  if (h != 0 && td == 0) {
#pragma unroll
    for (int r = 0; r < RQ; ++r) pm[h - 1][wq][tq * RQ + r] = m[r];
  }
  __syncthreads();

  // ---- epilogue: sqrt + partial mean (h==0, td==0 lanes only) ----
  float local = 0.0f;
  if (h == 0 && td == 0) {
#pragma unroll
    for (int r = 0; r < RQ; ++r) {
      float mr = m[r];
      mr = fmin3(mr, pm[0][wq][tq * RQ + r], pm[1][wq][tq * RQ + r]);
      mr = fminf(mr, pm[2][wq][tq * RQ + r]);
      local += sqrtf(fmaxf(q2[r] + mr, 0.0f) + 1e-6f);
    }
    local *= (1.0f / (float)(NB * NP));
  }

  // wave reduce, then block reduce, one atomic per block
#pragma unroll
  for (int off2 = 32; off2 > 0; off2 >>= 1)
    local += __shfl_down(local, off2);

  __shared__ float wsum[BLK / 64];
  if (lane == 0) wsum[wid] = local;
  __syncthreads();
  if (threadIdx.x == 0) {
    float s = 0.0f;
#pragma unroll
    for (int w = 0; w < BLK / 64; ++w) s += wsum[w];
    atomicAdd(out, s);
  }
}

extern "C" void kernel_launch(void* const* d_in, const int* in_sizes, int n_in,
                              void* d_out, int out_size, void* d_ws, size_t ws_size,
                              hipStream_t stream) {
  const float* x = (const float*)d_in[0];
  const float* y = (const float*)d_in[1];
  float* out = (float*)d_out;

  chamfer_init<<<1, 64, 0, stream>>>(out);
  chamfer_main<<<NBLOCKS, BLK, 0, stream>>>(x, y, out);
}

// Round 4
// 91.941 us; speedup vs baseline: 1.0937x; 1.0787x over previous
//
#include <hip/hip_runtime.h>

// ChamferLoss: x,y (16,4096,3) f32 -> scalar.
// R12: MFMA rewrite. R9-R11 proved the f32-VALU roofline: 3 structurally
// different kernels all at ~48us = 4.06 cyc per VALU wave-instr with the
// invariant 114.7K instr/CU. Escape: sq[i][j] = q2+d2-2q.d is matmul-shaped.
// One mfma_f32_32x32x16_bf16 per 32x32 tile, K-slots packed with split-bf16
// (s=-2q hi/lo x d hi/lo + d2/q2 hi/lo via 1-slots) -> full sq in the
// accumulator, err ~1e-4 in sq (~1e-6 in final mean). BOTH chamfer
// directions reduced from the same tile: per-x min in-register across
// j-tiles; per-y min via in-lane 16-reg tree + shfl_xor(32), per-wave LDS
// regions (race-free), cross-block combine via atomicMin on uint-cast
// floats in d_ws (needs 512KB), final kernel does sqrt+mean.
// Floors: MFMA 3.4us, VALU ~20/tile = 4-8us, DS 2/tile (conflict-free
// consecutive-16B-unit frag layout). Target 20-28us total.

#define NP 4096
#define NB 16
#define BLK 256
#define NBLOCKS (NB * 4 * 32)   // 2048: b(16) x js(4) x ic(32)

typedef float f32x16 __attribute__((ext_vector_type(16)));
typedef short s16x8 __attribute__((ext_vector_type(8)));

__device__ __forceinline__ float fmin3f(float a, float b, float c) {
  float d;
  asm("v_min3_f32 %0, %1, %2, %3" : "=v"(d) : "v"(a), "v"(b), "v"(c));
  return d;
}

__device__ __forceinline__ unsigned short f2bf(float v) {
  unsigned u = __float_as_uint(v);
  u += 0x7FFFu + ((u >> 16) & 1u);        // RNE to bf16
  return (unsigned short)(u >> 16);
}
__device__ __forceinline__ float bf2f(unsigned short s) {
  return __uint_as_float(((unsigned)s) << 16);
}

__global__ __launch_bounds__(256) void chamfer_init(unsigned* __restrict__ ws,
                                                    float* __restrict__ out) {
  const int i = blockIdx.x * 256 + threadIdx.x;   // grid 512 -> 131072
  ws[i] = 0x7F800000u;                            // +inf
  if (i == 0) out[0] = 0.0f;
}

// K-slot layout (A = x-queries as rows, B = y-points as cols):
//  k0-2 : sh(x,y,z) * dh(x,y,z)     (s = -2*q, split hi)
//  k3-5 : sh * dl
//  k6-8 : sl * dh
//  k9,10: 1 * d2h, 1 * d2l
//  k11,12: q2h * 1, q2l * 1
//  k13-15: 0
// A-frag lane l: row=l%32, k=(l/32)*8+i ; B-frag: col=l%32, k=(l/32)*8+i.
// C/D: col=lane&31, row=(reg&3)+8*(reg>>2)+4*(lane>>5)  [verified m74/m101]

__global__ __launch_bounds__(BLK) void chamfer_main(
    const float* __restrict__ x, const float* __restrict__ y,
    unsigned* __restrict__ ws) {
  const int bid = blockIdx.x;
  const int b  = bid >> 7;
  const int js = (bid >> 5) & 3;
  const int ic = bid & 31;

  const float* xb = x + ((size_t)b * NP + ic * 128) * 3;
  const float* yb = y + ((size_t)b * NP + js * 1024) * 3;

  __shared__ s16x8 yfrag[1024 * 2];   // 32 KB: unit (jt*64 + lane) = 16B
  __shared__ float m2s[4][1024];      // 16 KB: per-wave y-min regions
  __shared__ float m1s[128];          // per-block x-mins

  const int tid  = threadIdx.x;
  const int lane = tid & 63;
  const int w    = tid >> 6;
  const int row  = lane & 31;
  const int hf   = lane >> 5;
  const short ONE = (short)0x3F80;    // bf16(1.0)

  // ---- A-frag: this lane's x-point (row), split-bf16 packed ----
  const float qx = xb[(w * 32 + row) * 3 + 0];
  const float qy = xb[(w * 32 + row) * 3 + 1];
  const float qz = xb[(w * 32 + row) * 3 + 2];
  const float sx = -2.0f * qx, sy = -2.0f * qy, sz = -2.0f * qz;
  const unsigned short shx = f2bf(sx), shy = f2bf(sy), shz = f2bf(sz);
  const unsigned short slx = f2bf(sx - bf2f(shx));
  const unsigned short sly = f2bf(sy - bf2f(shy));
  const unsigned short slz = f2bf(sz - bf2f(shz));
  const float q2 = fmaf(qx, qx, fmaf(qy, qy, qz * qz));
  const unsigned short q2h = f2bf(q2);
  const unsigned short q2l = f2bf(q2 - bf2f(q2h));
  const s16x8 a0 = {(short)shx, (short)shy, (short)shz,
                    (short)shx, (short)shy, (short)shz,
                    (short)slx, (short)sly};
  const s16x8 a1 = {(short)slz, ONE, ONE, (short)q2h, (short)q2l, 0, 0, 0};
  const s16x8 afr = hf ? a1 : a0;

  // ---- stage y slice (1024 pts) as prepacked B-frag halves ----
  for (int k = 0; k < 4; ++k) {
    const int j = tid + k * 256;
    const float y0 = yb[j * 3 + 0];
    const float y1 = yb[j * 3 + 1];
    const float y2 = yb[j * 3 + 2];
    const unsigned short dh0 = f2bf(y0), dh1 = f2bf(y1), dh2 = f2bf(y2);
    const unsigned short dl0 = f2bf(y0 - bf2f(dh0));
    const unsigned short dl1 = f2bf(y1 - bf2f(dh1));
    const unsigned short dl2 = f2bf(y2 - bf2f(dh2));
    const float d2 = fmaf(y0, y0, fmaf(y1, y1, y2 * y2));
    const unsigned short d2h = f2bf(d2);
    const unsigned short d2l = f2bf(d2 - bf2f(d2h));
    const s16x8 h0 = {(short)dh0, (short)dh1, (short)dh2,
                      (short)dl0, (short)dl1, (short)dl2,
                      (short)dh0, (short)dh1};
    const s16x8 h1 = {(short)dh2, (short)d2h, (short)d2l, ONE, ONE, 0, 0, 0};
    const int jt = j >> 5, jc = j & 31;
    yfrag[jt * 64 + jc]      = h0;    // read by lanes 0..31
    yfrag[jt * 64 + 32 + jc] = h1;    // read by lanes 32..63
  }
  __syncthreads();

  // ---- main loop: 32 j-tiles, 1 MFMA each, both reductions fused ----
  float m1[16];
#pragma unroll
  for (int r = 0; r < 16; ++r) m1[r] = 3.4e38f;
  const f32x16 zc = {};
  const s16x8* base = &yfrag[0] + lane;     // ds addr = lane*16 (+ jt*1024 imm)

#pragma unroll
  for (int jt = 0; jt < 32; jt += 2) {
    const s16x8 b0 = base[jt * 64];
    const s16x8 b1 = base[(jt + 1) * 64];
    const f32x16 d0 = __builtin_amdgcn_mfma_f32_32x32x16_bf16(afr, b0, zc, 0, 0, 0);
    const f32x16 d1 = __builtin_amdgcn_mfma_f32_32x32x16_bf16(afr, b1, zc, 0, 0, 0);
    // dir1: per-x running min (rows fixed per reg, cols advance with jt)
#pragma unroll
    for (int r = 0; r < 16; ++r) m1[r] = fmin3f(d0[r], d1[r], m1[r]);
    // dir2: per-y tile min = in-lane tree over 16 rows + cross-half
    float c0 = fminf(
        fmin3f(fmin3f(d0[0], d0[1], d0[2]), fmin3f(d0[3], d0[4], d0[5]), d0[15]),
        fmin3f(fmin3f(d0[6], d0[7], d0[8]), fmin3f(d0[9], d0[10], d0[11]),
               fmin3f(d0[12], d0[13], d0[14])));
    float c1 = fminf(
        fmin3f(fmin3f(d1[0], d1[1], d1[2]), fmin3f(d1[3], d1[4], d1[5]), d1[15]),
        fmin3f(fmin3f(d1[6], d1[7], d1[8]), fmin3f(d1[9], d1[10], d1[11]),
               fmin3f(d1[12], d1[13], d1[14])));
    c0 = fminf(c0, __shfl_xor(c0, 32));
    c1 = fminf(c1, __shfl_xor(c1, 32));
    m2s[w][jt * 32 + row]       = c0;  // lanes l,l+32 same addr, same value
    m2s[w][(jt + 1) * 32 + row] = c1;
  }

  // ---- dir1 endgame: min across the 32 cols, then park in m1s ----
#pragma unroll
  for (int s = 1; s <= 16; s <<= 1) {
#pragma unroll
    for (int r = 0; r < 16; ++r) m1[r] = fminf(m1[r], __shfl_xor(m1[r], s));
  }
  if ((lane & 31) == 0) {
#pragma unroll
    for (int r = 0; r < 16; ++r) {
      const int rw = (r & 3) + 8 * (r >> 2) + 4 * hf;
      m1s[w * 32 + rw] = m1[r];
    }
  }
  __syncthreads();

  // ---- cross-block combine via atomicMin on uint-cast floats ----
  if (tid < 128) {
    const float v = fmaxf(m1s[tid], 0.0f);
    atomicMin(&ws[(size_t)b * NP + ic * 128 + tid], __float_as_uint(v));
  }
#pragma unroll
  for (int k = 0; k < 4; ++k) {
    const int j = tid + k * 256;
    float v = fminf(fminf(m2s[0][j], m2s[1][j]), fminf(m2s[2][j], m2s[3][j]));
    v = fmaxf(v, 0.0f);
    atomicMin(&ws[65536 + (size_t)b * NP + js * 1024 + j], __float_as_uint(v));
  }
}

__global__ __launch_bounds__(256) void chamfer_final(
    const unsigned* __restrict__ ws, float* __restrict__ out) {
  const int i = blockIdx.x * 256 + threadIdx.x;   // grid 512 -> 131072
  float s = sqrtf(__uint_as_float(ws[i]) + 1e-6f);
#pragma unroll
  for (int off = 32; off > 0; off >>= 1) s += __shfl_down(s, off);
  __shared__ float wsum[4];
  if ((threadIdx.x & 63) == 0) wsum[threadIdx.x >> 6] = s;
  __syncthreads();
  if (threadIdx.x == 0)
    atomicAdd(out, (wsum[0] + wsum[1] + wsum[2] + wsum[3]) * (1.0f / 65536.0f));
}

extern "C" void kernel_launch(void* const* d_in, const int* in_sizes, int n_in,
                              void* d_out, int out_size, void* d_ws, size_t ws_size,
                              hipStream_t stream) {
  const float* x = (const float*)d_in[0];
  const float* y = (const float*)d_in[1];
  float* out = (float*)d_out;
  unsigned* ws = (unsigned*)d_ws;   // needs 131072 * 4 = 512 KB

  chamfer_init<<<512, 256, 0, stream>>>(ws, out);
  chamfer_main<<<NBLOCKS, BLK, 0, stream>>>(x, y, ws);
  chamfer_final<<<512, 256, 0, stream>>>(ws, out);
}